// Round 1
// 679.957 us; speedup vs baseline: 1.3885x; 1.3885x over previous
//
#include <hip/hip_runtime.h>
#include <hip/hip_bf16.h>

// Problem dims
#define BB 64
#define TT 168
#define NN 64
#define FF 17
#define HID 128
#define GATES 512   // 4*HID
#define NLAYERS 4
#define NROWS (BB*TT)   // 10752

// LSTM pipeline chunking
#define CH 8
#define NCHUNK (TT/CH)  // 21

// Workspace layout (float offsets)
#define WS_W1SRC 0
#define WS_W1DST 32
#define WS_W2SRC 64
#define WS_W2DST 192
#define WS_BSUM  320                    // 4*512 -> ends 2368
#define WS_WD    2560                   // 17 (pad 32): W1 @ (W2 @ a2dst)
#define WS_WSV   2592                   // 17 (pad 32): W1 @ (W2 @ a2src)
#define WS_W12   2624                   // 17*128 = 2176: W1 @ W2
#define WS_WXG0T 4800                   // 512*20 (17 used): (W12 @ Wih0^T)^T rows
#define WS_FLAGS 16000                  // 256 ints: per-(layer,batch) progress counters
#define WS_XG    1395712                // NROWS*512 = 5505024 (layer-0 gates from GAT)
#define WS_HSEQ0 6900736                // 4 buffers of NROWS*HID
#define HSEQ_SZ  1376256

// LDS-only barrier: s_waitcnt lgkmcnt(0) + raw s_barrier (no vmcnt drain).
__device__ __forceinline__ void lds_barrier() {
    __asm__ volatile("" ::: "memory");
    __builtin_amdgcn_s_waitcnt(0xc07f);
    __builtin_amdgcn_s_barrier();
    __asm__ volatile("" ::: "memory");
}

__device__ __forceinline__ float fsig(float x) {
    return __builtin_amdgcn_rcpf(1.f + __expf(-x));
}
__device__ __forceinline__ float ftanh(float x) {
    float e = __expf(2.f * x);
    return 1.f - 2.f * __builtin_amdgcn_rcpf(e + 1.f);
}
__device__ __forceinline__ float bcast_lane(float v, int lane) {
    return __int_as_float(__builtin_amdgcn_readlane(__float_as_int(v), lane));
}

// ---------------- prep1: attention projection vectors + bias sums + flag reset ----------------
__global__ void prep1(const float* __restrict__ W1, const float* __restrict__ a1,
                      const float* __restrict__ W2, const float* __restrict__ a2,
                      const float* __restrict__ bih, const float* __restrict__ bhh,
                      float* __restrict__ ws) {
    int tid = threadIdx.x;
    if (tid < 34) {
        int f = tid % FF, half = tid / FF;
        float acc = 0.f;
        for (int o = 0; o < HID; o++) acc += W1[f*HID + o] * a1[half*HID + o];
        ws[(half ? WS_W1DST : WS_W1SRC) + f] = acc;
    }
    {
        int k = tid & 127, half = tid >> 7;
        float acc = 0.f;
        for (int o = 0; o < HID; o++) acc += W2[k*HID + o] * a2[half*HID + o];
        ws[(half ? WS_W2DST : WS_W2SRC) + k] = acc;
    }
    for (int idx = tid; idx < NLAYERS*GATES; idx += 256) ws[WS_BSUM + idx] = bih[idx] + bhh[idx];
    // reset pipeline flags (agent-scope so lstm_pipe's coherent loads see zeros)
    __hip_atomic_store((int*)(ws + WS_FLAGS) + tid, 0,
                       __ATOMIC_RELAXED, __HIP_MEMORY_SCOPE_AGENT);
}

// ---------------- prep2: W12 = W1 @ W2 (17 x 128) ----------------
__global__ void prep2(const float* __restrict__ W1, const float* __restrict__ W2,
                      float* __restrict__ ws) {
    int f = blockIdx.x, o = threadIdx.x;
    float acc = 0.f;
    for (int k = 0; k < HID; k++) acc += W1[f*HID + k] * W2[k*HID + o];
    ws[WS_W12 + f*HID + o] = acc;
}

// ---------------- prep3: WD/WSV (17 each) + WXG0T (512 x 17, stride 20) ----------------
__global__ void prep3(const float* __restrict__ W1, const float* __restrict__ Wih0,
                      float* __restrict__ ws) {
    int idx = blockIdx.x * 256 + threadIdx.x;
    if (idx < 17) {
        int f = idx;
        float acc = 0.f;
        for (int k = 0; k < HID; k++) acc += W1[f*HID + k] * ws[WS_W2DST + k];
        ws[WS_WD + f] = acc;
    } else if (idx < 34) {
        int f = idx - 17;
        float acc = 0.f;
        for (int k = 0; k < HID; k++) acc += W1[f*HID + k] * ws[WS_W2SRC + k];
        ws[WS_WSV + f] = acc;
    } else if (idx < 34 + GATES*FF) {
        int e = idx - 34;
        int j = e % GATES, f = e / GATES;   // f < 17
        float acc = 0.f;
        for (int o = 0; o < HID; o++) acc += ws[WS_W12 + f*HID + o] * Wih0[j*HID + o];
        ws[WS_WXG0T + j*20 + f] = acc;
    }
}

// ---------------- K1: fused GAT1 + GAT2(site) -> Xg layer-0 directly ----------------
struct __align__(16) GatSmem {
    float attn[64*68];       // P2 writes rows (stride 68), P3 reads
    float xsT[FF*64];        // [f][n]
    float xbarT[FF*68];      // [f][i], stride 68
    float src1[64], dst1[64], rinv[64], att2[64];
    float xbar2[20];
    float part_x[FF*8];      // P5a partials
    unsigned long long adjbits[64];
};
// ~28.5 KB -> 5 blocks/CU

__global__ __launch_bounds__(256) void gat_fused(const float* __restrict__ x, const int* __restrict__ adj,
                                                 const float* __restrict__ ws,
                                                 float* __restrict__ Xg, const int* __restrict__ site_ptr) {
    __shared__ GatSmem sm;
    const int tid = threadIdx.x;
    const int tt = blockIdx.x, bb = blockIdx.y;
    const int site = site_ptr[0];
    const int r = bb*TT + tt;
    const float* xblk = x + (size_t)r * (NN*FF);

    // P0: x transposed into LDS, adjacency bitmasks
    for (int idx = tid; idx < NN*FF; idx += 256) {
        int n = idx / FF, f = idx % FF;
        sm.xsT[f*64 + n] = xblk[idx];
    }
    {
        int w = tid >> 6, lane = tid & 63;
        for (int rr = w*16; rr < w*16 + 16; rr++) {
            int val = adj[rr*64 + lane];
            unsigned long long m = __ballot(val > 0);
            if (lane == 0) sm.adjbits[rr] = m | (1ull << rr);
        }
    }
    lds_barrier();

    // P1: src1/dst1 = x . (W1 @ a1-halves)
    if (tid < 128) {
        int n = tid & 63, half = tid >> 6;
        const float* wv = ws + (half ? WS_W1DST : WS_W1SRC);
        float acc = 0.f;
        #pragma unroll
        for (int f = 0; f < FF; f++) acc += sm.xsT[f*64 + n] * wv[f];
        if (half) sm.dst1[n] = acc; else sm.src1[n] = acc;
    }
    lds_barrier();

    // P2: attention logits -> exp -> attn rows
    {
        int q = tid & 3, i = tid >> 2;
        unsigned long long ab = sm.adjbits[i];
        float si = sm.src1[i];
        float v[16];
        float vmax = -1e30f;
        #pragma unroll
        for (int u = 0; u < 16; u++) {
            int jj = q*16 + u;
            float e = si + sm.dst1[jj];
            float lv = fmaxf(e, 0.2f*e);
            lv = ((ab >> jj) & 1ull) ? lv : -1e9f;
            v[u] = lv;
            vmax = fmaxf(vmax, lv);
        }
        vmax = fmaxf(vmax, __shfl_xor(vmax, 1, 4));
        vmax = fmaxf(vmax, __shfl_xor(vmax, 2, 4));
        float s = 0.f;
        float* arow = &sm.attn[i*68];
        #pragma unroll
        for (int w = 0; w < 4; w++) {
            float4 pv;
            pv.x = __expf(v[w*4+0] - vmax);
            pv.y = __expf(v[w*4+1] - vmax);
            pv.z = __expf(v[w*4+2] - vmax);
            pv.w = __expf(v[w*4+3] - vmax);
            s += (pv.x + pv.y) + (pv.z + pv.w);
            *(float4*)(arow + q*16 + w*4) = pv;
        }
        s += __shfl_xor(s, 1, 4);
        s += __shfl_xor(s, 2, 4);
        if (q == 0) sm.rinv[i] = 1.f / s;
    }
    lds_barrier();

    // P3: xbarT[f][i] = (P @ X)[i][f] * rinv
    {
        int i = tid & 63, q = tid >> 6;
        const float* arow = &sm.attn[i*68];
        float acc[5] = {0.f,0.f,0.f,0.f,0.f};
        const int nf = (q == 0) ? 5 : 4;
        for (int j4 = 0; j4 < 16; j4++) {
            float4 a4 = *(const float4*)(arow + j4*4);
            #pragma unroll
            for (int u = 0; u < 5; u++) {
                if (u < nf) {
                    int f = q + 4*u;
                    float4 x4 = *(const float4*)(&sm.xsT[f*64 + j4*4]);
                    acc[u] += a4.x*x4.x + a4.y*x4.y + a4.z*x4.z + a4.w*x4.w;
                }
            }
        }
        float ri = sm.rinv[i];
        #pragma unroll
        for (int u = 0; u < 5; u++) {
            if (u < nf) sm.xbarT[(q + 4*u)*68 + i] = acc[u] * ri;
        }
    }
    lds_barrier();

    // P4' (wave 0): dst2[j] = xbar[j].WD ; src2 = xbar[site].WSV ; softmax -> att2
    if (tid < 64) {
        int jj = tid;
        float d = 0.f, sp = 0.f;
        #pragma unroll
        for (int f = 0; f < FF; f++) {
            float xv = sm.xbarT[f*68 + jj];
            float xs = sm.xbarT[f*68 + site];
            d  += xv * ws[WS_WD + f];
            sp += xs * ws[WS_WSV + f];
        }
        unsigned long long ab = sm.adjbits[site];
        float e = sp + d;
        float lv = fmaxf(e, 0.2f*e);
        lv = ((ab >> jj) & 1ull) ? lv : -1e9f;
        float m = lv;
        #pragma unroll
        for (int dd = 1; dd < 64; dd <<= 1) m = fmaxf(m, __shfl_xor(m, dd));
        float p = __expf(lv - m);
        float s = p;
        #pragma unroll
        for (int dd = 1; dd < 64; dd <<= 1) s += __shfl_xor(s, dd);
        sm.att2[jj] = p / s;
    }
    lds_barrier();

    // P5a: xbar2 partials
    if (tid < FF*8) {
        int f = tid >> 3, c = tid & 7;
        float p = 0.f;
        #pragma unroll
        for (int u = 0; u < 8; u++) {
            int i = c*8 + u;
            p += sm.att2[i] * sm.xbarT[f*68 + i];
        }
        sm.part_x[f*8 + c] = p;
    }
    lds_barrier();

    // P5b: reduce xbar2
    if (tid < FF) {
        float s = 0.f;
        #pragma unroll
        for (int c = 0; c < 8; c++) s += sm.part_x[tid*8 + c];
        sm.xbar2[tid] = s;
    }
    lds_barrier();

    // P6': Xg0[r][j] = xbar2 . WXG0T[j] + bsum0[j]
    {
        float xb[FF];
        #pragma unroll
        for (int f = 0; f < FF; f++) xb[f] = sm.xbar2[f];
        #pragma unroll
        for (int half = 0; half < 2; half++) {
            int j = tid + half*256;
            const float4* wp = (const float4*)(ws + WS_WXG0T + j*20);
            float4 w0 = wp[0], w1 = wp[1], w2 = wp[2], w3 = wp[3];
            float wlast = ws[WS_WXG0T + j*20 + 16];
            float acc = ws[WS_BSUM + j];
            acc += w0.x*xb[0] + w0.y*xb[1] + w0.z*xb[2] + w0.w*xb[3];
            acc += w1.x*xb[4] + w1.y*xb[5] + w1.z*xb[6] + w1.w*xb[7];
            acc += w2.x*xb[8] + w2.y*xb[9] + w2.z*xb[10] + w2.w*xb[11];
            acc += w3.x*xb[12] + w3.y*xb[13] + w3.z*xb[14] + w3.w*xb[15];
            acc += wlast*xb[16];
            Xg[(size_t)r*GATES + j] = acc;
        }
    }
}

// ---------------- K2: all-layer pipelined recurrence ----------------
// Grid: (BB, NLAYERS) = 256 blocks of 512 threads. __launch_bounds__(512) caps
// VGPR<=256 -> every CU holds >=1 block -> all 256 blocks co-resident -> the
// cross-layer spin-waits cannot deadlock (layer l waits only on l-1).
//
// Layer l, batch b runs the 168-step recurrence in chunks of CH=8 steps.
//  - Layer 0 reads its gates from Xg (GAT output) via a double-buffered LDS
//    stage prefetched one chunk ahead.
//  - Layers 1..3 wait on flags[(l-1)*BB+b] >= (c+1)*CH, load h_{l-1} for the
//    chunk with agent-scope (cross-XCD coherent) loads, and compute the input
//    GEMM  xg[t][j] = bsum[j] + Wih[j,:] . h_prev[t,:]  inline (Wih streamed
//    from L2 each chunk; Whh already fills the register budget).
//  - Producers (l<3) store h with agent-scope relaxed stores; at chunk end:
//    s_waitcnt vmcnt(0) by all threads -> s_barrier -> tid0 publishes flag.
//
// Recurrence core (unchanged from the 944us kernel): thread (kc=tid>>7,
// jj=tid&127) computes Whh partials for gates {jj,128+jj,256+jj,384+jj} over
// k-chunk kc via register-resident weights + readlane broadcast of h (held in
// lanes 0..31 of each wave, wave pairs redundant); one LDS barrier per step;
// part[] double-buffered.
__global__ __launch_bounds__(512, 1) void lstm_pipe(const float* __restrict__ Xg0,
                                                    const float* __restrict__ Wih,
                                                    const float* __restrict__ Whh,
                                                    float* __restrict__ ws) {
    const int b = blockIdx.x;
    const int l = blockIdx.y;
    const int tid = threadIdx.x;
    const int lane = tid & 63;
    const int kc = tid >> 7;                 // 0..3, shared by wave pairs
    const int jj = tid & 127;                // A-partial output slot
    const int o = kc*32 + (lane & 31);       // B output owned by lanes<32
    const bool blane = (lane < 32);
    const bool storer = ((tid >> 6) & 1) == 0;   // first wave of each kc pair stores

    __shared__ __align__(16) float part[2][4][128][4];   // 16 KB
    __shared__ __align__(16) float xg[2][CH*GATES];      // 32 KB (l>0 uses xg[0] only)
    __shared__ __align__(16) float xs[CH*HID];           // 4 KB  (l>0: h_prev chunk)

    int* flags = (int*)(ws + WS_FLAGS);

    // Whh fragment -> registers
    float w[4][32];
    {
        const float* Whh_l = Whh + (size_t)l*GATES*HID;
        #pragma unroll
        for (int u = 0; u < 4; u++) {
            const float4* wr = (const float4*)(Whh_l + (size_t)(u*128 + jj)*HID + kc*32);
            #pragma unroll
            for (int k4 = 0; k4 < 8; k4++) {
                float4 v = wr[k4];
                w[u][k4*4+0] = v.x; w[u][k4*4+1] = v.y; w[u][k4*4+2] = v.z; w[u][k4*4+3] = v.w;
            }
        }
    }

    const float* xg_g  = Xg0 + (size_t)b*TT*GATES;
    float*       hout  = ws + WS_HSEQ0 + (size_t)l*HSEQ_SZ + (size_t)b*TT*HID;
    const float* hprev = (l > 0) ? (ws + WS_HSEQ0 + (size_t)(l-1)*HSEQ_SZ + (size_t)b*TT*HID)
                                 : ws;
    const float* Wih_l = Wih + (size_t)l*GATES*HID;
    const float  bsum_j = ws[WS_BSUM + l*GATES + tid];

    float h_own = 0.f, c_own = 0.f;
    float4 pf0 = {0,0,0,0}, pf1 = {0,0,0,0};
    int buf = 0;

    if (l == 0) {
        // stage chunk 0 of Xg into xg[0]
        const float4* g4 = (const float4*)xg_g;
        float4 v0 = g4[tid], v1 = g4[512 + tid];
        float4* d = (float4*)xg[0];
        d[tid] = v0; d[512 + tid] = v1;
        lds_barrier();
    }

    for (int c = 0; c < NCHUNK; c++) {
        if (l == 0) {
            // issue next chunk's Xg loads (completes during this chunk's steps)
            if (c + 1 < NCHUNK) {
                const float4* g4 = (const float4*)(xg_g + (size_t)(c+1)*CH*GATES);
                pf0 = g4[tid]; pf1 = g4[512 + tid];
            }
        } else {
            // wait for producer to publish chunk c
            if (tid == 0) {
                int* flg = &flags[(l-1)*BB + b];
                const int need = (c + 1)*CH;
                while (__hip_atomic_load(flg, __ATOMIC_RELAXED, __HIP_MEMORY_SCOPE_AGENT) < need)
                    __builtin_amdgcn_s_sleep(8);
            }
            lds_barrier();                        // also guards xg[0] overwrite vs last chunk's B reads
            // coherent load of h_prev chunk -> xs
            #pragma unroll
            for (int q = 0; q < 2; q++) {
                int idx = q*512 + tid;
                xs[idx] = __hip_atomic_load(&hprev[(size_t)c*CH*HID + idx],
                                            __ATOMIC_RELAXED, __HIP_MEMORY_SCOPE_AGENT);
            }
            lds_barrier();
            // input GEMM: thread tid = gate j, all CH timesteps
            float acc[CH];
            #pragma unroll
            for (int t = 0; t < CH; t++) acc[t] = bsum_j;
            const float4* wr = (const float4*)(Wih_l + (size_t)tid*HID);
            #pragma unroll
            for (int kq = 0; kq < 4; kq++) {
                float4 wv[8];
                #pragma unroll
                for (int q = 0; q < 8; q++) wv[q] = wr[kq*8 + q];
                #pragma unroll
                for (int t = 0; t < CH; t++) {
                    const float4* xp = (const float4*)(xs + t*HID + kq*32);
                    float a = 0.f;
                    #pragma unroll
                    for (int q = 0; q < 8; q++) {
                        float4 xv = xp[q];
                        a += wv[q].x*xv.x + wv[q].y*xv.y + wv[q].z*xv.z + wv[q].w*xv.w;
                    }
                    acc[t] += a;
                }
            }
            #pragma unroll
            for (int t = 0; t < CH; t++) xg[0][t*GATES + tid] = acc[t];
            lds_barrier();
        }

        const float* xgbuf = xg[(l == 0) ? buf : 0];

        // CH recurrence steps
        for (int tc = 0; tc < CH; tc++) {
            const int t = c*CH + tc;
            float xgc[4];
            if (blane) {
                #pragma unroll
                for (int u = 0; u < 4; u++) xgc[u] = xgbuf[tc*GATES + u*HID + o];
            }
            // A: Whh partial matvec; h broadcast from lane registers
            float a0 = 0.f, a1 = 0.f, a2 = 0.f, a3 = 0.f;
            #pragma unroll
            for (int k = 0; k < 32; k++) {
                float hv = bcast_lane(h_own, k);
                a0 += w[0][k]*hv; a1 += w[1][k]*hv; a2 += w[2][k]*hv; a3 += w[3][k]*hv;
            }
            float4 st = {a0, a1, a2, a3};
            *(float4*)(&part[t & 1][kc][jj][0]) = st;

            lds_barrier();

            // B: lanes 0..31 of every wave update their owned output (pairs redundant)
            if (blane) {
                float4 s4 = {xgc[0], xgc[1], xgc[2], xgc[3]};
                #pragma unroll
                for (int kcc = 0; kcc < 4; kcc++) {
                    float4 p = *(const float4*)(&part[t & 1][kcc][o][0]);
                    s4.x += p.x; s4.y += p.y; s4.z += p.z; s4.w += p.w;
                }
                float si = fsig(s4.x), sf = fsig(s4.y), so = fsig(s4.w);
                float tg = ftanh(s4.z);
                c_own = sf*c_own + si*tg;
                h_own = so*ftanh(c_own);
                if (storer)
                    __hip_atomic_store(&hout[t*HID + o], h_own,
                                       __ATOMIC_RELAXED, __HIP_MEMORY_SCOPE_AGENT);
            }
        }

        // chunk end: publish progress (l<3) / rotate layer-0 xg buffer
        if (l == 0) {
            __asm__ volatile("s_waitcnt vmcnt(0)" ::: "memory");   // h stores + pf loads done
            if (c + 1 < NCHUNK) {
                float4* d = (float4*)xg[buf ^ 1];
                d[tid] = pf0; d[512 + tid] = pf1;
                buf ^= 1;
            }
            lds_barrier();
            if (tid == 0)
                __hip_atomic_store(&flags[b], (c+1)*CH,
                                   __ATOMIC_RELAXED, __HIP_MEMORY_SCOPE_AGENT);
        } else if (l < NLAYERS - 1) {
            __asm__ volatile("s_waitcnt vmcnt(0)" ::: "memory");   // h stores done
            lds_barrier();
            if (tid == 0)
                __hip_atomic_store(&flags[l*BB + b], (c+1)*CH,
                                   __ATOMIC_RELAXED, __HIP_MEMORY_SCOPE_AGENT);
        }
    }
}

// ---------------- K4: final linear ----------------
__global__ void final_lin(const float* __restrict__ ws, const float* __restrict__ Wlin,
                          const float* __restrict__ blin, float* __restrict__ out) {
    const int b = blockIdx.x, l = threadIdx.x;  // 64 threads
    float acc = 0.f;
    #pragma unroll
    for (int u = 0; u < 8; u++) {
        int idx = u*64 + l;
        int layer = idx >> 7, k = idx & 127;
        const float* hs = ws + WS_HSEQ0 + (size_t)layer*HSEQ_SZ;
        acc += hs[((size_t)b*TT + (TT-1))*HID + k] * Wlin[idx];
    }
    #pragma unroll
    for (int d = 1; d < 64; d <<= 1) acc += __shfl_xor(acc, d);
    if (l == 0) out[b] = acc + blin[0];
}

extern "C" void kernel_launch(void* const* d_in, const int* in_sizes, int n_in,
                              void* d_out, int out_size, void* d_ws, size_t ws_size,
                              hipStream_t stream) {
    const float* x    = (const float*)d_in[0];
    const int*   adj  = (const int*)d_in[1];
    const float* W1   = (const float*)d_in[2];
    const float* a1   = (const float*)d_in[3];
    const float* W2   = (const float*)d_in[4];
    const float* a2   = (const float*)d_in[5];
    const float* Wih  = (const float*)d_in[6];
    const float* Whh  = (const float*)d_in[7];
    const float* bih  = (const float*)d_in[8];
    const float* bhh  = (const float*)d_in[9];
    const float* Wlin = (const float*)d_in[10];
    const float* blin = (const float*)d_in[11];
    const int*   site = (const int*)d_in[12];
    float* ws  = (float*)d_ws;
    float* out = (float*)d_out;

    prep1<<<1, 256, 0, stream>>>(W1, a1, W2, a2, bih, bhh, ws);
    prep2<<<FF, 128, 0, stream>>>(W1, W2, ws);
    prep3<<<35, 256, 0, stream>>>(W1, Wih, ws);
    gat_fused<<<dim3(TT, BB), 256, 0, stream>>>(x, adj, ws, ws + WS_XG, site);
    // all 4 layers concurrently, wavefront-pipelined via agent-scope flags
    lstm_pipe<<<dim3(BB, NLAYERS), 512, 0, stream>>>(ws + WS_XG, Wih, Whh, ws);
    final_lin<<<64, 64, 0, stream>>>(ws, Wlin, blin, out);
}

// Round 2
// 586.698 us; speedup vs baseline: 1.6092x; 1.1590x over previous
//
#include <hip/hip_runtime.h>
#include <hip/hip_bf16.h>

// Problem dims
#define BB 64
#define TT 168
#define NN 64
#define FF 17
#define HID 128
#define GATES 512   // 4*HID
#define NLAYERS 4
#define NROWS (BB*TT)   // 10752

// LSTM pipeline chunking
#define CH 8
#define NCHUNK (TT/CH)  // 21

// Workspace layout (float offsets)
#define WS_W1SRC 0
#define WS_W1DST 32
#define WS_W2SRC 64
#define WS_W2DST 192
#define WS_BSUM  320                    // 4*512 -> ends 2368
#define WS_WD    2560                   // 17 (pad 32): W1 @ (W2 @ a2dst)
#define WS_WSV   2592                   // 17 (pad 32): W1 @ (W2 @ a2src)
#define WS_W12   2624                   // 17*128 = 2176: W1 @ W2
#define WS_WXG0T 4800                   // 512*20 (17 used): (W12 @ Wih0^T)^T rows -> ends 15040
#define WS_ADJB  15104                  // 64 u64 adjacency bitmasks (128 floats) -> ends 15232
#define WS_FLAGS 16000                  // 256 ints: per-(layer,batch) progress counters
#define WS_XG    1395712                // NROWS*512 = 5505024 (layer-0 gates from GAT)
#define WS_HSEQ0 6900736                // 4 buffers of NROWS*HID
#define HSEQ_SZ  1376256

// LDS-only barrier: s_waitcnt lgkmcnt(0) + raw s_barrier (no vmcnt drain).
__device__ __forceinline__ void lds_barrier() {
    __asm__ volatile("" ::: "memory");
    __builtin_amdgcn_s_waitcnt(0xc07f);
    __builtin_amdgcn_s_barrier();
    __asm__ volatile("" ::: "memory");
}

__device__ __forceinline__ float fsig(float x) {
    return __builtin_amdgcn_rcpf(1.f + __expf(-x));
}
__device__ __forceinline__ float ftanh(float x) {
    float e = __expf(2.f * x);
    return 1.f - 2.f * __builtin_amdgcn_rcpf(e + 1.f);
}
__device__ __forceinline__ float bcast_lane(float v, int lane) {
    return __int_as_float(__builtin_amdgcn_readlane(__float_as_int(v), lane));
}

// ---------------- prep1: attention projection vectors + bias sums + adj bitmasks + flag reset ----------------
__global__ void prep1(const float* __restrict__ W1, const float* __restrict__ a1,
                      const float* __restrict__ W2, const float* __restrict__ a2,
                      const float* __restrict__ bih, const float* __restrict__ bhh,
                      const int* __restrict__ adj, float* __restrict__ ws) {
    int tid = threadIdx.x;
    if (tid < 34) {
        int f = tid % FF, half = tid / FF;
        float acc = 0.f;
        for (int o = 0; o < HID; o++) acc += W1[f*HID + o] * a1[half*HID + o];
        ws[(half ? WS_W1DST : WS_W1SRC) + f] = acc;
    }
    {
        int k = tid & 127, half = tid >> 7;
        float acc = 0.f;
        for (int o = 0; o < HID; o++) acc += W2[k*HID + o] * a2[half*HID + o];
        ws[(half ? WS_W2DST : WS_W2SRC) + k] = acc;
    }
    for (int idx = tid; idx < NLAYERS*GATES; idx += 256) ws[WS_BSUM + idx] = bih[idx] + bhh[idx];
    // adjacency bitmasks (with self-loop), computed once for all 10752 GAT blocks
    if (tid < 64) {
        unsigned long long m = 1ull << tid;
        const int* ar = adj + tid*64;
        for (int j = 0; j < 64; j++) if (ar[j] > 0) m |= (1ull << j);
        ((unsigned long long*)(ws + WS_ADJB))[tid] = m;
    }
    // reset pipeline flags (agent-scope so lstm_pipe's coherent loads see zeros)
    __hip_atomic_store((int*)(ws + WS_FLAGS) + tid, 0,
                       __ATOMIC_RELAXED, __HIP_MEMORY_SCOPE_AGENT);
}

// ---------------- prep2: W12 = W1 @ W2 (17 x 128) ----------------
__global__ void prep2(const float* __restrict__ W1, const float* __restrict__ W2,
                      float* __restrict__ ws) {
    int f = blockIdx.x, o = threadIdx.x;
    float acc = 0.f;
    for (int k = 0; k < HID; k++) acc += W1[f*HID + k] * W2[k*HID + o];
    ws[WS_W12 + f*HID + o] = acc;
}

// ---------------- prep3: WD/WSV (17 each) + WXG0T (512 x 17, stride 20) ----------------
__global__ void prep3(const float* __restrict__ W1, const float* __restrict__ Wih0,
                      float* __restrict__ ws) {
    int idx = blockIdx.x * 256 + threadIdx.x;
    if (idx < 17) {
        int f = idx;
        float acc = 0.f;
        for (int k = 0; k < HID; k++) acc += W1[f*HID + k] * ws[WS_W2DST + k];
        ws[WS_WD + f] = acc;
    } else if (idx < 34) {
        int f = idx - 17;
        float acc = 0.f;
        for (int k = 0; k < HID; k++) acc += W1[f*HID + k] * ws[WS_W2SRC + k];
        ws[WS_WSV + f] = acc;
    } else if (idx < 34 + GATES*FF) {
        int e = idx - 34;
        int j = e % GATES, f = e / GATES;   // f < 17
        float acc = 0.f;
        for (int o = 0; o < HID; o++) acc += ws[WS_W12 + f*HID + o] * Wih0[j*HID + o];
        ws[WS_WXG0T + j*20 + f] = acc;
    }
}

// ---------------- K1: fused GAT1 + GAT2(site) -> Xg layer-0 directly ----------------
struct __align__(16) GatSmem {
    float attn[64*68];       // P2 writes rows (stride 68), P3 reads
    float xsT[FF*64];        // [f][n]
    float xbarT[FF*68];      // [f][i], stride 68
    float src1[64], dst1[64], rinv[64], att2[64];
    float xbar2[20];
    float part_x[FF*8];      // P5a partials
    unsigned long long adjbits[64];
};
// ~28.5 KB -> 5 blocks/CU

__global__ __launch_bounds__(256) void gat_fused(const float* __restrict__ x, const int* __restrict__ adj,
                                                 const float* __restrict__ ws,
                                                 float* __restrict__ Xg, const int* __restrict__ site_ptr) {
    __shared__ GatSmem sm;
    const int tid = threadIdx.x;
    const int tt = blockIdx.x, bb = blockIdx.y;
    const int site = site_ptr[0];
    const int r = bb*TT + tt;
    const float* xblk = x + (size_t)r * (NN*FF);

    // P0: x transposed into LDS, adjacency bitmasks from prep1
    for (int idx = tid; idx < NN*FF; idx += 256) {
        int n = idx / FF, f = idx % FF;
        sm.xsT[f*64 + n] = xblk[idx];
    }
    if (tid < 64) sm.adjbits[tid] = ((const unsigned long long*)(ws + WS_ADJB))[tid];
    lds_barrier();

    // P1: src1/dst1 = x . (W1 @ a1-halves)
    if (tid < 128) {
        int n = tid & 63, half = tid >> 6;
        const float* wv = ws + (half ? WS_W1DST : WS_W1SRC);
        float acc = 0.f;
        #pragma unroll
        for (int f = 0; f < FF; f++) acc += sm.xsT[f*64 + n] * wv[f];
        if (half) sm.dst1[n] = acc; else sm.src1[n] = acc;
    }
    lds_barrier();

    // P2: attention logits -> exp -> attn rows
    {
        int q = tid & 3, i = tid >> 2;
        unsigned long long ab = sm.adjbits[i];
        float si = sm.src1[i];
        float v[16];
        float vmax = -1e30f;
        #pragma unroll
        for (int u = 0; u < 16; u++) {
            int jj = q*16 + u;
            float e = si + sm.dst1[jj];
            float lv = fmaxf(e, 0.2f*e);
            lv = ((ab >> jj) & 1ull) ? lv : -1e9f;
            v[u] = lv;
            vmax = fmaxf(vmax, lv);
        }
        vmax = fmaxf(vmax, __shfl_xor(vmax, 1, 4));
        vmax = fmaxf(vmax, __shfl_xor(vmax, 2, 4));
        float s = 0.f;
        float* arow = &sm.attn[i*68];
        #pragma unroll
        for (int w = 0; w < 4; w++) {
            float4 pv;
            pv.x = __expf(v[w*4+0] - vmax);
            pv.y = __expf(v[w*4+1] - vmax);
            pv.z = __expf(v[w*4+2] - vmax);
            pv.w = __expf(v[w*4+3] - vmax);
            s += (pv.x + pv.y) + (pv.z + pv.w);
            *(float4*)(arow + q*16 + w*4) = pv;
        }
        s += __shfl_xor(s, 1, 4);
        s += __shfl_xor(s, 2, 4);
        if (q == 0) sm.rinv[i] = 1.f / s;
    }
    lds_barrier();

    // P3: xbarT[f][i] = (P @ X)[i][f] * rinv
    {
        int i = tid & 63, q = tid >> 6;
        const float* arow = &sm.attn[i*68];
        float acc[5] = {0.f,0.f,0.f,0.f,0.f};
        const int nf = (q == 0) ? 5 : 4;
        for (int j4 = 0; j4 < 16; j4++) {
            float4 a4 = *(const float4*)(arow + j4*4);
            #pragma unroll
            for (int u = 0; u < 5; u++) {
                if (u < nf) {
                    int f = q + 4*u;
                    float4 x4 = *(const float4*)(&sm.xsT[f*64 + j4*4]);
                    acc[u] += a4.x*x4.x + a4.y*x4.y + a4.z*x4.z + a4.w*x4.w;
                }
            }
        }
        float ri = sm.rinv[i];
        #pragma unroll
        for (int u = 0; u < 5; u++) {
            if (u < nf) sm.xbarT[(q + 4*u)*68 + i] = acc[u] * ri;
        }
    }
    lds_barrier();

    // P4' (wave 0): dst2[j] = xbar[j].WD ; src2 = xbar[site].WSV ; softmax -> att2
    if (tid < 64) {
        int jj = tid;
        float d = 0.f, sp = 0.f;
        #pragma unroll
        for (int f = 0; f < FF; f++) {
            float xv = sm.xbarT[f*68 + jj];
            float xs = sm.xbarT[f*68 + site];
            d  += xv * ws[WS_WD + f];
            sp += xs * ws[WS_WSV + f];
        }
        unsigned long long ab = sm.adjbits[site];
        float e = sp + d;
        float lv = fmaxf(e, 0.2f*e);
        lv = ((ab >> jj) & 1ull) ? lv : -1e9f;
        float m = lv;
        #pragma unroll
        for (int dd = 1; dd < 64; dd <<= 1) m = fmaxf(m, __shfl_xor(m, dd));
        float p = __expf(lv - m);
        float s = p;
        #pragma unroll
        for (int dd = 1; dd < 64; dd <<= 1) s += __shfl_xor(s, dd);
        sm.att2[jj] = p / s;
    }
    lds_barrier();

    // P5a: xbar2 partials
    if (tid < FF*8) {
        int f = tid >> 3, c = tid & 7;
        float p = 0.f;
        #pragma unroll
        for (int u = 0; u < 8; u++) {
            int i = c*8 + u;
            p += sm.att2[i] * sm.xbarT[f*68 + i];
        }
        sm.part_x[f*8 + c] = p;
    }
    lds_barrier();

    // P5b: reduce xbar2
    if (tid < FF) {
        float s = 0.f;
        #pragma unroll
        for (int c = 0; c < 8; c++) s += sm.part_x[tid*8 + c];
        sm.xbar2[tid] = s;
    }
    lds_barrier();

    // P6': Xg0[r][j] = xbar2 . WXG0T[j] + bsum0[j]
    {
        float xb[FF];
        #pragma unroll
        for (int f = 0; f < FF; f++) xb[f] = sm.xbar2[f];
        #pragma unroll
        for (int half = 0; half < 2; half++) {
            int j = tid + half*256;
            const float4* wp = (const float4*)(ws + WS_WXG0T + j*20);
            float4 w0 = wp[0], w1 = wp[1], w2 = wp[2], w3 = wp[3];
            float wlast = ws[WS_WXG0T + j*20 + 16];
            float acc = ws[WS_BSUM + j];
            acc += w0.x*xb[0] + w0.y*xb[1] + w0.z*xb[2] + w0.w*xb[3];
            acc += w1.x*xb[4] + w1.y*xb[5] + w1.z*xb[6] + w1.w*xb[7];
            acc += w2.x*xb[8] + w2.y*xb[9] + w2.z*xb[10] + w2.w*xb[11];
            acc += w3.x*xb[12] + w3.y*xb[13] + w3.z*xb[14] + w3.w*xb[15];
            acc += wlast*xb[16];
            Xg[(size_t)r*GATES + j] = acc;
        }
    }
}

// ---------------- K2: all-layer pipelined recurrence, ingemm hidden in rec steps ----------------
// Grid: (BB, NLAYERS) = 256 blocks of 512 threads, 1 block/CU, all co-resident
// -> cross-layer spin-waits cannot deadlock (layer l waits only on l-1; producers free-run).
//
// Consumers (l>0) no longer run a serial per-chunk input GEMM. During chunk c's
// 8 recurrence steps, each step's B-phase executes one 16-k slice of the input
// GEMM for chunk c+1 (all 512 threads; thread = gate). The slice's Wih weights
// (4 float4) are prefetched one step ahead in registers (rotating; identical
// every chunk). xs (h_prev chunk) and xg (gate buffer) are double-buffered.
// The slice's VALU/LDS/vmem work rides in the recurrence's stall slack
// (rec is latency-bound: VALUBusy 33%, LDS pipe mostly idle).
//
// Chunk start (l>0, c+1<NCHUNK): wait flag >= (c+2)*CH, stage h_prev chunk c+1
// into xs[(c+1)&1] (drained by step-0's A-barrier). Chunk end (all layers):
// vmcnt(0) drain + lds_barrier (+ flag publish for l<3).
__global__ __launch_bounds__(512, 1) void lstm_pipe(const float* __restrict__ Xg0,
                                                    const float* __restrict__ Wih,
                                                    const float* __restrict__ Whh,
                                                    float* __restrict__ ws) {
    const int b = blockIdx.x;
    const int l = blockIdx.y;
    const int tid = threadIdx.x;
    const int lane = tid & 63;
    const int kc = tid >> 7;                 // 0..3, shared by wave pairs
    const int jj = tid & 127;                // A-partial output slot
    const int o = kc*32 + (lane & 31);       // B output owned by lanes<32
    const bool blane = (lane < 32);
    const bool storer = ((tid >> 6) & 1) == 0;   // first wave of each kc pair stores

    __shared__ __align__(16) float part[2][4][128][4];   // 16 KB
    __shared__ __align__(16) float xg[2][CH*GATES];      // 32 KB
    __shared__ __align__(16) float xs[2][CH*HID];        // 8 KB

    int* flags = (int*)(ws + WS_FLAGS);

    // Whh fragment -> registers
    float w[4][32];
    {
        const float* Whh_l = Whh + (size_t)l*GATES*HID;
        #pragma unroll
        for (int u = 0; u < 4; u++) {
            const float4* wr2 = (const float4*)(Whh_l + (size_t)(u*128 + jj)*HID + kc*32);
            #pragma unroll
            for (int k4 = 0; k4 < 8; k4++) {
                float4 v = wr2[k4];
                w[u][k4*4+0] = v.x; w[u][k4*4+1] = v.y; w[u][k4*4+2] = v.z; w[u][k4*4+3] = v.w;
            }
        }
    }

    const float* xg_g  = Xg0 + (size_t)b*TT*GATES;
    float*       hout  = ws + WS_HSEQ0 + (size_t)l*HSEQ_SZ + (size_t)b*TT*HID;
    const float* hprev = (l > 0) ? (ws + WS_HSEQ0 + (size_t)(l-1)*HSEQ_SZ + (size_t)b*TT*HID)
                                 : ws;
    const float* Wih_l = Wih + (size_t)l*GATES*HID;
    const float  bsum_j = ws[WS_BSUM + l*GATES + tid];
    const float4* wr = (const float4*)(Wih_l + (size_t)tid*HID);   // this thread's Wih row

    float h_own = 0.f, c_own = 0.f;
    float4 pf0 = {0,0,0,0}, pf1 = {0,0,0,0};
    int buf = 0;

    float acc[CH];                 // next-chunk ingemm accumulators (l>0)
    float4 wv0, wv1, wv2, wv3;     // current-slice Wih weights (l>0)

    if (l == 0) {
        // stage chunk 0 of Xg into xg[0]
        const float4* g4 = (const float4*)xg_g;
        float4 v0 = g4[tid], v1 = g4[512 + tid];
        float4* d = (float4*)xg[0];
        d[tid] = v0; d[512 + tid] = v1;
        lds_barrier();
    } else {
        // prologue: wait chunk 0, stage xs[0], serial ingemm -> xg[0]
        if (tid == 0) {
            int* flg = &flags[(l-1)*BB + b];
            while (__hip_atomic_load(flg, __ATOMIC_RELAXED, __HIP_MEMORY_SCOPE_AGENT) < CH)
                __builtin_amdgcn_s_sleep(8);
        }
        lds_barrier();
        #pragma unroll
        for (int q = 0; q < 2; q++) {
            int idx = q*512 + tid;
            xs[0][idx] = __hip_atomic_load(&hprev[idx],
                                           __ATOMIC_RELAXED, __HIP_MEMORY_SCOPE_AGENT);
        }
        lds_barrier();
        float a0[CH];
        #pragma unroll
        for (int t = 0; t < CH; t++) a0[t] = bsum_j;
        #pragma unroll
        for (int kq = 0; kq < 4; kq++) {
            float4 wvv[8];
            #pragma unroll
            for (int q = 0; q < 8; q++) wvv[q] = wr[kq*8 + q];
            #pragma unroll
            for (int t = 0; t < CH; t++) {
                const float4* xp = (const float4*)(&xs[0][t*HID + kq*32]);
                float a = 0.f;
                #pragma unroll
                for (int q = 0; q < 8; q++) {
                    float4 xv = xp[q];
                    a += wvv[q].x*xv.x + wvv[q].y*xv.y + wvv[q].z*xv.z + wvv[q].w*xv.w;
                }
                a0[t] += a;
            }
        }
        #pragma unroll
        for (int t = 0; t < CH; t++) xg[0][t*GATES + tid] = a0[t];
        // init slice state for the interleaved pipeline
        wv0 = wr[0]; wv1 = wr[1]; wv2 = wr[2]; wv3 = wr[3];
        #pragma unroll
        for (int t = 0; t < CH; t++) acc[t] = bsum_j;
        lds_barrier();
    }

    for (int c = 0; c < NCHUNK; c++) {
        const bool have_next = (c + 1 < NCHUNK);

        if (l == 0) {
            if (have_next) {
                const float4* g4 = (const float4*)(xg_g + (size_t)(c+1)*CH*GATES);
                pf0 = g4[tid]; pf1 = g4[512 + tid];
            }
        } else if (have_next) {
            // wait for producer to publish chunk c+1, stage it into xs[(c+1)&1]
            if (tid == 0) {
                int* flg = &flags[(l-1)*BB + b];
                const int need = (c + 2)*CH;
                while (__hip_atomic_load(flg, __ATOMIC_RELAXED, __HIP_MEMORY_SCOPE_AGENT) < need)
                    __builtin_amdgcn_s_sleep(8);
            }
            lds_barrier();
            float v0 = __hip_atomic_load(&hprev[(size_t)(c+1)*CH*HID + tid],
                                         __ATOMIC_RELAXED, __HIP_MEMORY_SCOPE_AGENT);
            float v1 = __hip_atomic_load(&hprev[(size_t)(c+1)*CH*HID + 512 + tid],
                                         __ATOMIC_RELAXED, __HIP_MEMORY_SCOPE_AGENT);
            xs[(c+1)&1][tid] = v0;
            xs[(c+1)&1][512 + tid] = v1;
            // ds_writes drained by step-0's A-barrier (lgkmcnt(0) before s_barrier)
        }

        const float* xgbuf = (l == 0) ? xg[buf] : xg[c & 1];
        const float* xsn = xs[(c+1)&1];
        float* xgn = xg[(c+1)&1];

        // CH recurrence steps (+ interleaved next-chunk ingemm slices for l>0)
        for (int tc = 0; tc < CH; tc++) {
            const int t = c*CH + tc;
            float xgc[4];
            if (blane) {
                #pragma unroll
                for (int u = 0; u < 4; u++) xgc[u] = xgbuf[tc*GATES + u*HID + o];
            }
            // A: Whh partial matvec; h broadcast from lane registers
            float a0 = 0.f, a1 = 0.f, a2 = 0.f, a3 = 0.f;
            #pragma unroll
            for (int k = 0; k < 32; k++) {
                float hv = bcast_lane(h_own, k);
                a0 += w[0][k]*hv; a1 += w[1][k]*hv; a2 += w[2][k]*hv; a3 += w[3][k]*hv;
            }
            float4 st = {a0, a1, a2, a3};
            *(float4*)(&part[t & 1][kc][jj][0]) = st;

            lds_barrier();

            // B1: ingemm slice tc (k in [tc*16, tc*16+16)) for chunk c+1, all threads
            if (l > 0 && have_next) {
                const int kb = tc*16;
                #pragma unroll
                for (int t2 = 0; t2 < CH; t2++) {
                    const float4* xp = (const float4*)(&xsn[t2*HID + kb]);
                    float4 x0 = xp[0], x1 = xp[1], x2 = xp[2], x3 = xp[3];
                    acc[t2] += wv0.x*x0.x + wv0.y*x0.y + wv0.z*x0.z + wv0.w*x0.w
                             + wv1.x*x1.x + wv1.y*x1.y + wv1.z*x1.z + wv1.w*x1.w
                             + wv2.x*x2.x + wv2.y*x2.y + wv2.z*x2.z + wv2.w*x2.w
                             + wv3.x*x3.x + wv3.y*x3.y + wv3.z*x3.z + wv3.w*x3.w;
                }
                // rotate to next slice's weights (wraps to slice 0 for next chunk)
                const int ns = (tc + 1) & 7;
                wv0 = wr[ns*4+0]; wv1 = wr[ns*4+1]; wv2 = wr[ns*4+2]; wv3 = wr[ns*4+3];
                if (tc == CH-1) {
                    #pragma unroll
                    for (int t2 = 0; t2 < CH; t2++) {
                        xgn[t2*GATES + tid] = acc[t2];
                        acc[t2] = bsum_j;
                    }
                }
            }

            // B2: lanes 0..31 of every wave update their owned output (pairs redundant)
            if (blane) {
                float4 s4 = {xgc[0], xgc[1], xgc[2], xgc[3]};
                #pragma unroll
                for (int kcc = 0; kcc < 4; kcc++) {
                    float4 p = *(const float4*)(&part[t & 1][kcc][o][0]);
                    s4.x += p.x; s4.y += p.y; s4.z += p.z; s4.w += p.w;
                }
                float si = fsig(s4.x), sf = fsig(s4.y), so = fsig(s4.w);
                float tg = ftanh(s4.z);
                c_own = sf*c_own + si*tg;
                h_own = so*ftanh(c_own);
                if (storer)
                    __hip_atomic_store(&hout[t*HID + o], h_own,
                                       __ATOMIC_RELAXED, __HIP_MEMORY_SCOPE_AGENT);
            }
        }

        // chunk end: drain h stores, barrier (xg/xs rotation safety), publish
        if (l == 0) {
            __asm__ volatile("s_waitcnt vmcnt(0)" ::: "memory");   // h stores + pf loads done
            if (have_next) {
                float4* d = (float4*)xg[buf ^ 1];
                d[tid] = pf0; d[512 + tid] = pf1;
                buf ^= 1;
            }
            lds_barrier();
            if (tid == 0)
                __hip_atomic_store(&flags[b], (c+1)*CH,
                                   __ATOMIC_RELAXED, __HIP_MEMORY_SCOPE_AGENT);
        } else {
            __asm__ volatile("s_waitcnt vmcnt(0)" ::: "memory");   // h stores done
            lds_barrier();
            if (l < NLAYERS - 1 && tid == 0)
                __hip_atomic_store(&flags[l*BB + b], (c+1)*CH,
                                   __ATOMIC_RELAXED, __HIP_MEMORY_SCOPE_AGENT);
        }
    }
}

// ---------------- K4: final linear ----------------
__global__ void final_lin(const float* __restrict__ ws, const float* __restrict__ Wlin,
                          const float* __restrict__ blin, float* __restrict__ out) {
    const int b = blockIdx.x, l = threadIdx.x;  // 64 threads
    float acc = 0.f;
    #pragma unroll
    for (int u = 0; u < 8; u++) {
        int idx = u*64 + l;
        int layer = idx >> 7, k = idx & 127;
        const float* hs = ws + WS_HSEQ0 + (size_t)layer*HSEQ_SZ;
        acc += hs[((size_t)b*TT + (TT-1))*HID + k] * Wlin[idx];
    }
    #pragma unroll
    for (int d = 1; d < 64; d <<= 1) acc += __shfl_xor(acc, d);
    if (l == 0) out[b] = acc + blin[0];
}

extern "C" void kernel_launch(void* const* d_in, const int* in_sizes, int n_in,
                              void* d_out, int out_size, void* d_ws, size_t ws_size,
                              hipStream_t stream) {
    const float* x    = (const float*)d_in[0];
    const int*   adj  = (const int*)d_in[1];
    const float* W1   = (const float*)d_in[2];
    const float* a1   = (const float*)d_in[3];
    const float* W2   = (const float*)d_in[4];
    const float* a2   = (const float*)d_in[5];
    const float* Wih  = (const float*)d_in[6];
    const float* Whh  = (const float*)d_in[7];
    const float* bih  = (const float*)d_in[8];
    const float* bhh  = (const float*)d_in[9];
    const float* Wlin = (const float*)d_in[10];
    const float* blin = (const float*)d_in[11];
    const int*   site = (const int*)d_in[12];
    float* ws  = (float*)d_ws;
    float* out = (float*)d_out;

    prep1<<<1, 256, 0, stream>>>(W1, a1, W2, a2, bih, bhh, adj, ws);
    prep2<<<FF, 128, 0, stream>>>(W1, W2, ws);
    prep3<<<35, 256, 0, stream>>>(W1, Wih, ws);
    gat_fused<<<dim3(TT, BB), 256, 0, stream>>>(x, adj, ws, ws + WS_XG, site);
    // all 4 layers concurrently, wavefront-pipelined via agent-scope flags
    lstm_pipe<<<dim3(BB, NLAYERS), 512, 0, stream>>>(ws + WS_XG, Wih, Whh, ws);
    final_lin<<<64, 64, 0, stream>>>(ws, Wlin, blin, out);
}